// Round 4
// baseline (222.697 us; speedup 1.0000x reference)
//
#include <hip/hip_runtime.h>

#define NB   2048
#define SEQ  200
#define DIM  64
#define NH1  64
#define NH2  16
#define EPSF 1e-9f

typedef float fvec4 __attribute__((ext_vector_type(4)));
typedef short svec8 __attribute__((ext_vector_type(8)));   // 8 bf16 = 4 VGPRs

// workspace layout (bytes); total 540672 B
#define WS_BFRAG_OFF 0        // 16 KB : phase-1 B frags [c:4][kk:4][slot:64][8] bf16
#define WS_QTERM_OFF 16384    // 512 KB : qterm[2048][64] f32

__device__ __forceinline__ short f2bf(float f) {
    unsigned u = __float_as_uint(f);
    u += 0x7fffu + ((u >> 16) & 1u);      // round-to-nearest-even
    return (short)(u >> 16);
}

// ---------------- prep: blocks 0-3 build the batch-independent B-frags
//                  [Wbc ; W1d]; blocks 4-131 compute qterm = q @ (W1a+W1c).
__global__ __launch_bounds__(256)
void din_prep_kernel(const float* __restrict__ q,
                     const float* __restrict__ W1,
                     char* __restrict__ ws)
{
    __shared__ float wac[64 * 64];   // (W1a+W1c)[d][h]
    __shared__ float qs[16 * 64];    // this block's 16 q rows
    const int t = threadIdx.x;

    if (blockIdx.x < 4) {
        // B-frag entry e = (c*4+kk)*64 + slot; slot = qq*16+mm.
        // Element j has K = kk*32+qq*8+j, h = c*16+mm:
        //   K<64 -> Wbc[K][h] = (W1b-W1c)[K][h] ; K>=64 -> W1d[K-64][h]
        const int e  = blockIdx.x * 256 + t;    // 0..1023
        const int c  = e >> 8;
        const int kk = (e >> 6) & 3;
        const int sl = e & 63;
        const int qq = sl >> 4;
        const int mm = sl & 15;
        const int h  = c * 16 + mm;
        svec8 v;
        #pragma unroll
        for (int j = 0; j < 8; ++j) {
            const int K = kk * 32 + qq * 8 + j;
            const int d = K & 63;
            const float x = (K < 64)
                ? (W1[(64 + d) * NH1 + h] - W1[(128 + d) * NH1 + h])
                : W1[(192 + d) * NH1 + h];
            v[j] = f2bf(x);
        }
        *(svec8*)(ws + WS_BFRAG_OFF + e * 16) = v;
    } else {
        const int b0 = (blockIdx.x - 4) * 16;   // 128 blocks x 16 batches
        #pragma unroll
        for (int i = 0; i < 16; ++i) {
            const int idx = i * 256 + t;        // = d*64 + h
            wac[idx] = W1[idx] + W1[128 * NH1 + idx];
        }
        #pragma unroll
        for (int i = 0; i < 4; ++i) {
            const int idx = i * 256 + t;        // = bl*64 + d
            qs[idx] = q[(size_t)b0 * DIM + idx];
        }
        __syncthreads();
        const int lane = t & 63;
        const int wave = t >> 6;
        float* qt = (float*)(ws + WS_QTERM_OFF);
        #pragma unroll
        for (int bb = 0; bb < 4; ++bb) {
            const int bl = wave * 4 + bb;
            float acc = 0.f;
            #pragma unroll 8
            for (int d = 0; d < 64; ++d)
                acc = fmaf(qs[bl * 64 + d], wac[d * 64 + lane], acc);
            qt[(size_t)(b0 + bl) * 64 + lane] = acc;
        }
    }
}

// ---------------- main: zero W1 reads, zero barriers before the epilogue
#define H1F_OFF   0        // 8192 B : 4 x 2KB per-wave h1 transpose buffers
#define OUTP_OFF  8192     // 1024 B : cross-wave out partials
#define SMEM_BYTES 9216

__global__ __launch_bounds__(256, 3)
void din_attn_kernel(const float* __restrict__ q,        // [B,64]
                     const float* __restrict__ key,      // [B,200,64]
                     const int*   __restrict__ seqlen,   // [B,1]
                     const char*  __restrict__ ws,       // prepped frags+qterm
                     const float* __restrict__ alpha1v,
                     const float* __restrict__ mean1v,
                     const float* __restrict__ var1v,
                     const float* __restrict__ W2,       // [64,16]
                     const float* __restrict__ alpha2v,
                     const float* __restrict__ mean2v,
                     const float* __restrict__ var2v,
                     const float* __restrict__ W3,       // [16]
                     float* __restrict__ out)            // [B,64]
{
    __shared__ __align__(16) char smem[SMEM_BYTES];
    char*  h1f  = smem + H1F_OFF;
    float* outp = (float*)(smem + OUTP_OFF);

    const int b    = blockIdx.x;
    const int t    = threadIdx.x;
    const int lane = t & 63;
    const int wave = __builtin_amdgcn_readfirstlane(t >> 6);
    const int qd4  = lane >> 4;     // quad 0..3
    const int m    = lane & 15;

    int nseq = seqlen[b];
    nseq = nseq < SEQ ? nseq : SEQ;

    // Wbc frags (kk=0,1) resident in registers; W1d frags (kk=2,3) stay in
    // L1 and are re-read per iteration (anti-hoist below keeps them there).
    svec8 wcf[4][2];
    #pragma unroll
    for (int c = 0; c < 4; ++c)
        #pragma unroll
        for (int kk = 0; kk < 2; ++kk)
            wcf[c][kk] = *(const svec8*)(ws + WS_BFRAG_OFF +
                                         (((c << 2) | kk) << 10) + (lane << 4));

    // W2 frags, consumed as the A operand of the transposed phase-2
    svec8 w2f[2];
    #pragma unroll
    for (int kk = 0; kk < 2; ++kk) {
        svec8 f;
        #pragma unroll
        for (int j = 0; j < 8; ++j) {
            const int h = kk * 32 + qd4 * 8 + j;
            f[j] = f2bf(W2[h * NH2 + m]);
        }
        w2f[kk] = f;
    }

    // q row fragments (for the k*q half of the K=128 contraction)
    const float* qrow = q + (size_t)b * DIM;
    const fvec4 qv0 = *(const fvec4*)(qrow + (qd4 << 3));
    const fvec4 qv1 = *(const fvec4*)(qrow + (qd4 << 3) + 4);
    const fvec4 qv2 = *(const fvec4*)(qrow + 32 + (qd4 << 3));
    const fvec4 qv3 = *(const fvec4*)(qrow + 36 + (qd4 << 3));

    // per-batch bias qterm[b][c*16+m]
    const float* qtg = (const float*)(ws + WS_QTERM_OFF) + (size_t)b * 64;
    float qtermv[4];
    #pragma unroll
    for (int c = 0; c < 4; ++c) qtermv[c] = qtg[c * 16 + m];

    // dice1 params for h = c*16 + m
    float a1p[4], m1p[4], r1p[4];
    #pragma unroll
    for (int c = 0; c < 4; ++c) {
        a1p[c] = alpha1v[c * 16 + m];
        m1p[c] = mean1v[c * 16 + m];
        r1p[c] = rsqrtf(var1v[c * 16 + m] + EPSF);
    }
    // dice2 params for j = qd4*4 + reg (transposed phase-2 output rows)
    float a2p[4], m2p[4], r2p[4], w3p[4];
    #pragma unroll
    for (int reg = 0; reg < 4; ++reg) {
        const int j = qd4 * 4 + reg;
        a2p[reg] = alpha2v[j];
        m2p[reg] = mean2v[j];
        r2p[reg] = rsqrtf(var2v[j] + EPSF);
        w3p[reg] = W3[j];
    }

    char* myh1 = h1f + (wave << 11);   // 2 KB private transpose buffer
    const float* kb = key + (size_t)b * (SEQ * DIM);

    fvec4 oa0 = (fvec4){0.f,0.f,0.f,0.f};
    fvec4 oa1 = (fvec4){0.f,0.f,0.f,0.f};
    fvec4 oa2 = (fvec4){0.f,0.f,0.f,0.f};
    fvec4 oa3 = (fvec4){0.f,0.f,0.f,0.f};

    // ---- barrier-free main loop: wave owns rows [rb, rb+16), rb += 64
    for (int rb = wave * 16; rb < nseq; rb += 64) {
        int rm = rb + m;
        rm = rm < SEQ ? rm : SEQ - 1;              // garbage rows -> w=0
        const float* arow = kb + rm * DIM + (qd4 << 3);
        const fvec4 f0 = *(const fvec4*)(arow);
        const fvec4 f1 = *(const fvec4*)(arow + 4);
        const fvec4 f2 = *(const fvec4*)(arow + 32);
        const fvec4 f3 = *(const fvec4*)(arow + 36);

        svec8 a0, a1, a2, a3;                      // [k | k*q] A-frags
        #pragma unroll
        for (int jj = 0; jj < 4; ++jj) {
            a0[jj]     = f2bf(f0[jj]);
            a0[jj + 4] = f2bf(f1[jj]);
            a1[jj]     = f2bf(f2[jj]);
            a1[jj + 4] = f2bf(f3[jj]);
            a2[jj]     = f2bf(f0[jj] * qv0[jj]);
            a2[jj + 4] = f2bf(f1[jj] * qv1[jj]);
            a3[jj]     = f2bf(f2[jj] * qv2[jj]);
            a3[jj + 4] = f2bf(f3[jj] * qv3[jj]);
        }

        // anti-hoist: opaque zero keeps the W1d frag loads inside the loop
        // (hoisting them costs 32 VGPRs -> spills; see round-3 post-mortem)
        int zoff = 0;
        asm volatile("" : "+v"(zoff));
        const char* wldb = ws + WS_BFRAG_OFF + zoff + (lane << 4);

        // ---- phase 1: x = [k | k*q] @ [Wbc ; W1d] + qterm
        fvec4 acc[4];
        #pragma unroll
        for (int c = 0; c < 4; ++c) {
            const svec8 wl0 = *(const svec8*)(wldb + (((c << 2) | 2) << 10));
            const svec8 wl1 = *(const svec8*)(wldb + (((c << 2) | 3) << 10));
            fvec4 a = (fvec4){qtermv[c], qtermv[c], qtermv[c], qtermv[c]};
            a = __builtin_amdgcn_mfma_f32_16x16x32_bf16(a0, wcf[c][0], a, 0, 0, 0);
            a = __builtin_amdgcn_mfma_f32_16x16x32_bf16(a1, wcf[c][1], a, 0, 0, 0);
            a = __builtin_amdgcn_mfma_f32_16x16x32_bf16(a2, wl0,      a, 0, 0, 0);
            a = __builtin_amdgcn_mfma_f32_16x16x32_bf16(a3, wl1,      a, 0, 0, 0);
            acc[c] = a;
        }

        // ---- dice1; h1 -> LDS in frag layout, XOR-swizzled slots
        #pragma unroll
        for (int c = 0; c < 4; ++c) {
            const int kk2 = c >> 1;
            const int qhi = (c & 1) * 2 + (m >> 3);
            #pragma unroll
            for (int reg = 0; reg < 4; ++reg) {
                const float x  = acc[c][reg];
                const float xn = (x - m1p[c]) * r1p[c];
                const float p  = 1.f / (1.f + __expf(-xn));
                const float h1 = x * (a1p[c] + p * (1.f - a1p[c]));
                const int l2  = (qhi << 4) | ((qd4 << 2) | reg);
                const int l2s = l2 ^ ((l2 >> 3) & 7);
                *(short*)(myh1 + (kk2 << 10) + (l2s << 4) + ((m & 7) << 1))
                    = f2bf(h1);
            }
        }
        // same-wave write->read; compiler inserts lgkmcnt, no barrier

        // ---- phase 2 (operand-swapped): h2^T = W2^T @ h1^T
        const int slot = lane ^ ((lane >> 3) & 7);
        const svec8 bb0 = *(const svec8*)(myh1 + (slot << 4));
        const svec8 bb1 = *(const svec8*)(myh1 + 1024 + (slot << 4));
        fvec4 acc2 = (fvec4){0.f, 0.f, 0.f, 0.f};
        acc2 = __builtin_amdgcn_mfma_f32_16x16x32_bf16(w2f[0], bb0, acc2, 0, 0, 0);
        acc2 = __builtin_amdgcn_mfma_f32_16x16x32_bf16(w2f[1], bb1, acc2, 0, 0, 0);

        // ---- dice2 + W3: in-lane partial over 4 j's, 2 shfl_xor
        float s = 0.f;
        #pragma unroll
        for (int reg = 0; reg < 4; ++reg) {
            const float x  = acc2[reg];
            const float xn = (x - m2p[reg]) * r2p[reg];
            const float p  = 1.f / (1.f + __expf(-xn));
            const float hd = x * (a2p[reg] + p * (1.f - a2p[reg]));
            s = fmaf(hd, w3p[reg], s);
        }
        s += __shfl_xor(s, 16);
        s += __shfl_xor(s, 32);
        const float w = (rb + m < nseq) ? 1.f / (1.f + __expf(-s)) : 0.f;

        // ---- phase 3: accumulate w * k-row from registers we already hold
        #pragma unroll
        for (int jj = 0; jj < 4; ++jj) {
            oa0[jj] = fmaf(w, f0[jj], oa0[jj]);
            oa1[jj] = fmaf(w, f1[jj], oa1[jj]);
            oa2[jj] = fmaf(w, f2[jj], oa2[jj]);
            oa3[jj] = fmaf(w, f3[jj], oa3[jj]);
        }
    }

    // ---- once-per-kernel reduce over the 16 m-lanes of each q-group
    #pragma unroll
    for (int step = 1; step < 16; step <<= 1) {
        #pragma unroll
        for (int jj = 0; jj < 4; ++jj) {
            oa0[jj] += __shfl_xor(oa0[jj], step);
            oa1[jj] += __shfl_xor(oa1[jj], step);
            oa2[jj] += __shfl_xor(oa2[jj], step);
            oa3[jj] += __shfl_xor(oa3[jj], step);
        }
    }
    if (m == 0) {
        float* op = outp + wave * 64 + (qd4 << 3);
        *(fvec4*)(op)          = oa0;
        *(fvec4*)(op + 4)      = oa1;
        *(fvec4*)(op + 32)     = oa2;
        *(fvec4*)(op + 36)     = oa3;
    }
    __syncthreads();
    if (t < 64) {
        out[(size_t)b * DIM + t] = (outp[t] + outp[64 + t]) +
                                   (outp[128 + t] + outp[192 + t]);
    }
}

extern "C" void kernel_launch(void* const* d_in, const int* in_sizes, int n_in,
                              void* d_out, int out_size, void* d_ws, size_t ws_size,
                              hipStream_t stream) {
    const float* q      = (const float*)d_in[0];
    const float* key    = (const float*)d_in[1];
    const int*   seqlen = (const int*)d_in[2];
    const float* W1     = (const float*)d_in[3];
    const float* alpha1 = (const float*)d_in[4];
    const float* mean1  = (const float*)d_in[5];
    const float* var1   = (const float*)d_in[6];
    const float* W2     = (const float*)d_in[7];
    const float* alpha2 = (const float*)d_in[8];
    const float* mean2  = (const float*)d_in[9];
    const float* var2   = (const float*)d_in[10];
    const float* W3     = (const float*)d_in[11];
    float* out          = (float*)d_out;
    char* ws            = (char*)d_ws;   // needs 540672 B

    din_prep_kernel<<<132, 256, 0, stream>>>(q, W1, ws);
    din_attn_kernel<<<NB, 256, 0, stream>>>(q, key, seqlen, ws,
                                            alpha1, mean1, var1,
                                            W2, alpha2, mean2, var2,
                                            W3, out);
}

// Round 5
// 214.697 us; speedup vs baseline: 1.0373x; 1.0373x over previous
//
#include <hip/hip_runtime.h>

#define NB   2048
#define SEQ  200
#define DIM  64
#define NH1  64
#define NH2  16
#define EPSF 1e-9f

typedef float fvec4 __attribute__((ext_vector_type(4)));
typedef short svec8 __attribute__((ext_vector_type(8)));   // 8 bf16 = 4 VGPRs

// LDS layout (bytes). One block serves batches b0, b0+1 SERIALLY.
//   wcb  : both batches' Wc B-frags, bf16, frag layout (persists whole kernel)
//   h1f  : 4 x 2KB per-wave h1 transpose buffers
//   qpart: qterm partials (setup), aliased by outp (epilogue, 2 KB)
//   qall : qterm[2][64] (live until each batch's loop starts)
#define WCB_OFF    0        // 16384 B
#define H1F_OFF    16384    // 8192 B
#define QPART_OFF  24576    // 2048 B : qpart [2][4][64] / outp [2][4][64] alias
#define QALL_OFF   26624    // 512 B  : qterm[2][64]
#define SMEM_BYTES 27136

__device__ __forceinline__ short f2bf(float f) {
    unsigned u = __float_as_uint(f);
    u += 0x7fffu + ((u >> 16) & 1u);      // round-to-nearest-even
    return (short)(u >> 16);
}

__global__ __launch_bounds__(256, 4)
void din_attn_kernel(const float* __restrict__ q,        // [B,64]
                     const float* __restrict__ key,      // [B,200,64]
                     const int*   __restrict__ seqlen,   // [B,1]
                     const float* __restrict__ W1,       // [256,64]
                     const float* __restrict__ alpha1v,
                     const float* __restrict__ mean1v,
                     const float* __restrict__ var1v,
                     const float* __restrict__ W2,       // [64,16]
                     const float* __restrict__ alpha2v,
                     const float* __restrict__ mean2v,
                     const float* __restrict__ var2v,
                     const float* __restrict__ W3,       // [16]
                     float* __restrict__ out)            // [B,64]
{
    __shared__ __align__(16) char smem[SMEM_BYTES];
    char*  wcb   = smem + WCB_OFF;
    char*  h1f   = smem + H1F_OFF;
    float* qpart = (float*)(smem + QPART_OFF);     // [2][4][64] setup
    float* qall  = (float*)(smem + QALL_OFF);      // [2][64]
    float* outp  = (float*)(smem + QPART_OFF);     // [2][4][64] epilogue alias

    const int b0   = blockIdx.x << 1;              // this block owns b0, b0+1
    const int t    = threadIdx.x;
    const int lane = t & 63;
    const int wave = __builtin_amdgcn_readfirstlane(t >> 6);
    const int qd4  = lane >> 4;     // quad 0..3
    const int m    = lane & 15;

    const float* q0 = q + (size_t)b0 * DIM;
    const float* q1 = q0 + DIM;

    int ns0 = seqlen[b0];     ns0 = ns0 < SEQ ? ns0 : SEQ;
    int ns1 = seqlen[b0 + 1]; ns1 = ns1 < SEQ ? ns1 : SEQ;

    // ---- setup 1: Wc = (W1b - W1c) + q[d]*W1d for BOTH batches from ONE
    //      W1 read, written as bf16 in frag layout; qterm partials.
    //      Element (d,h) -> frag=(h>>4)*2+(d>>5), slot=((d>>3)&3)*16+(h&15),
    //      byte j=(d&7)*2.   (numerics identical to the verified r2/r3 setup)
    {
        const int h  = lane;
        const int c  = h >> 4;
        const int mm = h & 15;
        float qt0 = 0.f, qt1 = 0.f;
        #pragma unroll
        for (int i = 0; i < 16; ++i) {
            const int d = wave * 16 + i;
            const float w1a  = W1[(d)       * NH1 + h];
            const float w1b  = W1[(64 + d)  * NH1 + h];
            const float w1c  = W1[(128 + d) * NH1 + h];
            const float w1dd = W1[(192 + d) * NH1 + h];
            const float wbc  = w1b - w1c;
            const float wac  = w1a + w1c;
            const float q0d  = q0[d];              // uniform -> s_load
            const float q1d  = q1[d];
            qt0 = fmaf(q0d, wac, qt0);
            qt1 = fmaf(q1d, wac, qt1);
            const int frag = (c << 1) | (d >> 5);
            const int ln   = (((d >> 3) & 3) << 4) | mm;
            const int off  = (frag << 10) + (ln << 4) + ((d & 7) << 1);
            *(short*)(wcb + off)        = f2bf(fmaf(q0d, w1dd, wbc));
            *(short*)(wcb + 8192 + off) = f2bf(fmaf(q1d, w1dd, wbc));
        }
        qpart[wave * 64 + h]       = qt0;
        qpart[256 + wave * 64 + h] = qt1;
    }
    __syncthreads();

    // ---- setup 2: qterm reduce for both batches; shared frags/params
    if (t < 128) {
        const int ob = t >> 6, h = t & 63;
        const float* p = qpart + (ob << 8);
        qall[(ob << 6) + h] = (p[h] + p[64 + h]) + (p[128 + h] + p[192 + h]);
    }

    // W2 frags, consumed as the A operand of the transposed phase-2:
    // A[row=j=m][k=h=kk*32+qd4*8+jj] = W2[h][j].  Batch-independent.
    svec8 w2f[2];
    #pragma unroll
    for (int kk = 0; kk < 2; ++kk) {
        svec8 f;
        #pragma unroll
        for (int j = 0; j < 8; ++j) {
            const int h = kk * 32 + qd4 * 8 + j;
            f[j] = f2bf(W2[h * NH2 + m]);
        }
        w2f[kk] = f;
    }

    // dice1 params for h = c*16 + m
    float a1p[4], m1p[4], r1p[4];
    #pragma unroll
    for (int c = 0; c < 4; ++c) {
        a1p[c] = alpha1v[c * 16 + m];
        m1p[c] = mean1v[c * 16 + m];
        r1p[c] = rsqrtf(var1v[c * 16 + m] + EPSF);
    }
    // dice2 params for j = qd4*4 + reg (transposed phase-2 output rows)
    float a2p[4], m2p[4], r2p[4], w3p[4];
    #pragma unroll
    for (int reg = 0; reg < 4; ++reg) {
        const int j = qd4 * 4 + reg;
        a2p[reg] = alpha2v[j];
        m2p[reg] = mean2v[j];
        r2p[reg] = rsqrtf(var2v[j] + EPSF);
        w3p[reg] = W3[j];
    }

    __syncthreads();   // wcb/qall ready; qpart reads done -> outp alias safe

    char* myh1 = h1f + (wave << 11);   // 2 KB private transpose buffer

    // ================= serial over the block's two batches =================
    #pragma unroll 1
    for (int bsel = 0; bsel < 2; ++bsel) {
        const int mynseq = bsel ? ns1 : ns0;
        const float* kb = key + (size_t)(b0 + bsel) * (SEQ * DIM);
        const char* mywcb = wcb + (bsel << 13);

        svec8 wcf[4][2];   // this batch's Wc B-frags (8 x ds_read_b128)
        #pragma unroll
        for (int c = 0; c < 4; ++c)
            #pragma unroll
            for (int kk = 0; kk < 2; ++kk)
                wcf[c][kk] = *(const svec8*)(mywcb + (((c << 1) | kk) << 10)
                                             + (lane << 4));
        float qtermv[4];
        #pragma unroll
        for (int c = 0; c < 4; ++c) qtermv[c] = qall[(bsel << 6) + c * 16 + m];

        fvec4 oa0 = (fvec4){0.f,0.f,0.f,0.f};   // out cols qd4*8+0..3
        fvec4 oa1 = (fvec4){0.f,0.f,0.f,0.f};   // out cols qd4*8+4..7
        fvec4 oa2 = (fvec4){0.f,0.f,0.f,0.f};   // out cols 32+qd4*8+0..3
        fvec4 oa3 = (fvec4){0.f,0.f,0.f,0.f};   // out cols 32+qd4*8+4..7

        // ---- barrier-free main loop: wave owns rows [rb, rb+16), rb += 64
        for (int rb = wave * 16; rb < mynseq; rb += 64) {
            int rm = rb + m;
            rm = rm < SEQ ? rm : SEQ - 1;          // garbage rows -> w=0
            const float* arow = kb + rm * DIM + (qd4 << 3);
            const fvec4 f0 = *(const fvec4*)(arow);
            const fvec4 f1 = *(const fvec4*)(arow + 4);
            const fvec4 f2 = *(const fvec4*)(arow + 32);
            const fvec4 f3 = *(const fvec4*)(arow + 36);
            svec8 a0, a1;
            #pragma unroll
            for (int jj = 0; jj < 4; ++jj) {
                a0[jj]     = f2bf(f0[jj]);
                a0[jj + 4] = f2bf(f1[jj]);
                a1[jj]     = f2bf(f2[jj]);
                a1[jj + 4] = f2bf(f3[jj]);
            }

            // ---- phase 1: x = k @ Wc + qterm (qterm in acc init)
            fvec4 acc[4];
            #pragma unroll
            for (int c = 0; c < 4; ++c) {
                fvec4 a = (fvec4){qtermv[c], qtermv[c], qtermv[c], qtermv[c]};
                a = __builtin_amdgcn_mfma_f32_16x16x32_bf16(a0, wcf[c][0], a, 0, 0, 0);
                a = __builtin_amdgcn_mfma_f32_16x16x32_bf16(a1, wcf[c][1], a, 0, 0, 0);
                acc[c] = a;
            }

            // ---- dice1; h1 -> LDS in frag layout, XOR-swizzled slots
            #pragma unroll
            for (int c = 0; c < 4; ++c) {
                const int kk2 = c >> 1;
                const int qhi = (c & 1) * 2 + (m >> 3);
                #pragma unroll
                for (int reg = 0; reg < 4; ++reg) {
                    const float x  = acc[c][reg];
                    const float xn = (x - m1p[c]) * r1p[c];
                    const float p  = 1.f / (1.f + __expf(-xn));
                    const float h1 = x * (a1p[c] + p * (1.f - a1p[c]));
                    const int l2  = (qhi << 4) | ((qd4 << 2) | reg);
                    const int l2s = l2 ^ ((l2 >> 3) & 7);
                    *(short*)(myh1 + (kk2 << 10) + (l2s << 4) + ((m & 7) << 1))
                        = f2bf(h1);
                }
            }
            // same-wave write->read; compiler inserts lgkmcnt, no barrier

            // ---- phase 2 (operand-swapped): h2^T = W2^T @ h1^T
            //      C[row=j=qd4*4+reg][col=seqrow=m]
            const int slot = lane ^ ((lane >> 3) & 7);
            const svec8 bb0 = *(const svec8*)(myh1 + (slot << 4));
            const svec8 bb1 = *(const svec8*)(myh1 + 1024 + (slot << 4));
            fvec4 acc2 = (fvec4){0.f, 0.f, 0.f, 0.f};
            acc2 = __builtin_amdgcn_mfma_f32_16x16x32_bf16(w2f[0], bb0, acc2, 0, 0, 0);
            acc2 = __builtin_amdgcn_mfma_f32_16x16x32_bf16(w2f[1], bb1, acc2, 0, 0, 0);

            // ---- dice2 + W3: in-lane partial over 4 j's, 2 shfl_xor over
            //      qd4 groups -> each lane holds s for its own row rb+m
            float s = 0.f;
            #pragma unroll
            for (int reg = 0; reg < 4; ++reg) {
                const float x  = acc2[reg];
                const float xn = (x - m2p[reg]) * r2p[reg];
                const float p  = 1.f / (1.f + __expf(-xn));
                const float hd = x * (a2p[reg] + p * (1.f - a2p[reg]));
                s = fmaf(hd, w3p[reg], s);
            }
            s += __shfl_xor(s, 16);
            s += __shfl_xor(s, 32);
            const float w = (rb + m < mynseq) ? 1.f / (1.f + __expf(-s)) : 0.f;

            // ---- phase 3: accumulate w * k-row from registers we hold
            #pragma unroll
            for (int jj = 0; jj < 4; ++jj) {
                oa0[jj] = fmaf(w, f0[jj], oa0[jj]);
                oa1[jj] = fmaf(w, f1[jj], oa1[jj]);
                oa2[jj] = fmaf(w, f2[jj], oa2[jj]);
                oa3[jj] = fmaf(w, f3[jj], oa3[jj]);
            }
        }

        // ---- per-batch reduce over the 16 m-lanes of each q-group
        #pragma unroll
        for (int step = 1; step < 16; step <<= 1) {
            #pragma unroll
            for (int jj = 0; jj < 4; ++jj) {
                oa0[jj] += __shfl_xor(oa0[jj], step);
                oa1[jj] += __shfl_xor(oa1[jj], step);
                oa2[jj] += __shfl_xor(oa2[jj], step);
                oa3[jj] += __shfl_xor(oa3[jj], step);
            }
        }
        if (m == 0) {
            float* op = outp + (bsel << 8) + wave * 64 + (qd4 << 3);
            *(fvec4*)(op)          = oa0;
            *(fvec4*)(op + 4)      = oa1;
            *(fvec4*)(op + 32)     = oa2;
            *(fvec4*)(op + 36)     = oa3;
        }
    }

    __syncthreads();
    if (t < 128) {
        const int ob = t >> 6, d = t & 63;
        const float* p = outp + (ob << 8);
        out[(size_t)(b0 + ob) * DIM + d] = (p[d] + p[64 + d]) +
                                           (p[128 + d] + p[192 + d]);
    }
}

extern "C" void kernel_launch(void* const* d_in, const int* in_sizes, int n_in,
                              void* d_out, int out_size, void* d_ws, size_t ws_size,
                              hipStream_t stream) {
    const float* q      = (const float*)d_in[0];
    const float* key    = (const float*)d_in[1];
    const int*   seqlen = (const int*)d_in[2];
    const float* W1     = (const float*)d_in[3];
    const float* alpha1 = (const float*)d_in[4];
    const float* mean1  = (const float*)d_in[5];
    const float* var1   = (const float*)d_in[6];
    const float* W2     = (const float*)d_in[7];
    const float* alpha2 = (const float*)d_in[8];
    const float* mean2  = (const float*)d_in[9];
    const float* var2   = (const float*)d_in[10];
    const float* W3     = (const float*)d_in[11];
    float* out          = (float*)d_out;

    din_attn_kernel<<<NB / 2, 256, 0, stream>>>(q, key, seqlen, W1,
                                                alpha1, mean1, var1,
                                                W2, alpha2, mean2, var2,
                                                W3, out);
}

// Round 6
// 181.789 us; speedup vs baseline: 1.2250x; 1.1810x over previous
//
#include <hip/hip_runtime.h>

#define NB   2048
#define SEQ  200
#define DIM  64
#define NH1  64
#define NH2  16
#define EPSF 1e-9f
#define LOG2E 1.442695040888963f

typedef float    fvec4 __attribute__((ext_vector_type(4)));
typedef short    svec8 __attribute__((ext_vector_type(8)));   // 8 bf16 = 4 VGPRs
typedef unsigned uvec4 __attribute__((ext_vector_type(4)));

// LDS layout (bytes). h1 transpose buffers alias the setup-only Wc frag
// region (fenced by the second __syncthreads).
#define WCB_OFF   0        // 8192 B : setup Wc B-frags / main-loop h1f (4 x 2KB)
#define QPART_OFF 8192     // 1024 B : qterm partials (setup) / outp (epilogue)
#define QALL_OFF  9216     // 256 B  : qterm[64]
#define SMEM_BYTES 9472

__device__ __forceinline__ short f2bf(float f) {
    unsigned u = __float_as_uint(f);
    u += 0x7fffu + ((u >> 16) & 1u);      // round-to-nearest-even
    return (short)(u >> 16);
}

// packed f32x2 -> bf16x2 (RNE), 1 instruction (no builtin on gfx950; T12)
__device__ __forceinline__ unsigned pkbf(float lo, float hi) {
    unsigned r;
    asm("v_cvt_pk_bf16_f32 %0, %1, %2" : "=v"(r) : "v"(lo), "v"(hi));
    return r;
}
// raw v_exp_f32: D = 2^S0
__device__ __forceinline__ float exp2fast(float x) {
    float r;
    asm("v_exp_f32 %0, %1" : "=v"(r) : "v"(x));
    return r;
}

__global__ __launch_bounds__(256, 3)
void din_attn_kernel(const float* __restrict__ q,        // [B,64]
                     const float* __restrict__ key,      // [B,200,64]
                     const int*   __restrict__ seqlen,   // [B,1]
                     const float* __restrict__ W1,       // [256,64]
                     const float* __restrict__ alpha1v,
                     const float* __restrict__ mean1v,
                     const float* __restrict__ var1v,
                     const float* __restrict__ W2,       // [64,16]
                     const float* __restrict__ alpha2v,
                     const float* __restrict__ mean2v,
                     const float* __restrict__ var2v,
                     const float* __restrict__ W3,       // [16]
                     float* __restrict__ out)            // [B,64]
{
    __shared__ __align__(16) char smem[SMEM_BYTES];
    char*  wcb   = smem + WCB_OFF;                 // setup Wc frags
    char*  h1f   = smem + WCB_OFF;                 // main-loop alias
    float* qpart = (float*)(smem + QPART_OFF);
    float* qall  = (float*)(smem + QALL_OFF);
    float* outp  = (float*)(smem + QPART_OFF);     // epilogue alias

    const int b    = blockIdx.x;
    const int t    = threadIdx.x;
    const int lane = t & 63;
    const int wave = __builtin_amdgcn_readfirstlane(t >> 6);
    const int qd4  = lane >> 4;     // quad 0..3
    const int m    = lane & 15;

    const float* qrow = q + (size_t)b * DIM;
    int nseq = seqlen[b];
    nseq = nseq < SEQ ? nseq : SEQ;

    // ---- setup 1: Wc = (W1b - W1c) + q[d]*W1d written as bf16 in frag
    //      layout; qterm partials.  Element (d,h) -> frag=(h>>4)*2+(d>>5),
    //      slot=((d>>3)&3)*16+(h&15), byte j=(d&7)*2.
    {
        const int h  = lane;
        const int c  = h >> 4;
        const int mm = h & 15;
        float qt = 0.f;
        #pragma unroll
        for (int i = 0; i < 16; ++i) {
            const int d = wave * 16 + i;
            const float qdv  = qrow[d];
            const float w1a  = W1[(d)       * NH1 + h];
            const float w1b  = W1[(64 + d)  * NH1 + h];
            const float w1c  = W1[(128 + d) * NH1 + h];
            const float w1dd = W1[(192 + d) * NH1 + h];
            const float wc   = (w1b - w1c) + qdv * w1dd;
            qt = fmaf(qdv, w1a + w1c, qt);
            const int frag = (c << 1) | (d >> 5);
            const int ln   = (((d >> 3) & 3) << 4) | mm;
            *(short*)(wcb + (frag << 10) + (ln << 4) + ((d & 7) << 1)) = f2bf(wc);
        }
        qpart[wave * 64 + h] = qt;
    }
    __syncthreads();

    // ---- setup 2: qterm reduce; frags to registers; params
    if (t < 64)
        qall[t] = (qpart[t] + qpart[64 + t]) + (qpart[128 + t] + qpart[192 + t]);

    svec8 wcf[4][2];   // Wc B-frags (phase-1 B operand)
    #pragma unroll
    for (int c = 0; c < 4; ++c)
        #pragma unroll
        for (int kk = 0; kk < 2; ++kk)
            wcf[c][kk] = *(const svec8*)(wcb + (((c << 1) | kk) << 10) + (lane << 4));

    // W2 frags, consumed as the *A* operand of the transposed phase-2:
    // A[row=j=m][k=h=kk*32+qd4*8+jj] = W2[h][j].
    svec8 w2f[2];
    #pragma unroll
    for (int kk = 0; kk < 2; ++kk) {
        svec8 f;
        #pragma unroll
        for (int j = 0; j < 8; ++j) {
            const int h = kk * 32 + qd4 * 8 + j;
            f[j] = f2bf(W2[h * NH2 + m]);
        }
        w2f[kk] = f;
    }

    // dice1 params for h = c*16 + m.  r1p pre-scaled by log2(e) so the
    // sigmoid uses raw v_exp_f32 (2^x); o1p = 1 - alpha precomputed.
    float a1p[4], o1p[4], m1p[4], r1p[4];
    #pragma unroll
    for (int c = 0; c < 4; ++c) {
        a1p[c] = alpha1v[c * 16 + m];
        o1p[c] = 1.f - a1p[c];
        m1p[c] = mean1v[c * 16 + m];
        r1p[c] = rsqrtf(var1v[c * 16 + m] + EPSF) * LOG2E;
    }
    // dice2 params for j = qd4*4 + reg (transposed phase-2 output rows)
    float a2p[4], o2p[4], m2p[4], r2p[4], w3p[4];
    #pragma unroll
    for (int reg = 0; reg < 4; ++reg) {
        const int j = qd4 * 4 + reg;
        a2p[reg] = alpha2v[j];
        o2p[reg] = 1.f - a2p[reg];
        m2p[reg] = mean2v[j];
        r2p[reg] = rsqrtf(var2v[j] + EPSF) * LOG2E;
        w3p[reg] = W3[j];
    }

    __syncthreads();   // wcb reads done -> h1f alias safe; qall ready

    float qtermv[4];
    #pragma unroll
    for (int c = 0; c < 4; ++c) qtermv[c] = qall[c * 16 + m];

    char* myh1 = h1f + (wave << 11);   // 2 KB private transpose buffer
    const float* kb = key + (size_t)b * (SEQ * DIM);

    fvec4 oa0 = (fvec4){0.f,0.f,0.f,0.f};   // out cols qd4*8+0..3
    fvec4 oa1 = (fvec4){0.f,0.f,0.f,0.f};   // out cols qd4*8+4..7
    fvec4 oa2 = (fvec4){0.f,0.f,0.f,0.f};   // out cols 32+qd4*8+0..3
    fvec4 oa3 = (fvec4){0.f,0.f,0.f,0.f};   // out cols 32+qd4*8+4..7

    // ---- barrier-free main loop: wave owns rows [rb, rb+16), rb += 64
    for (int rb = wave * 16; rb < nseq; rb += 64) {
        int rm = rb + m;
        rm = rm < SEQ ? rm : SEQ - 1;              // garbage rows -> w=0
        const float* arow = kb + rm * DIM + (qd4 << 3);
        const fvec4 f0 = *(const fvec4*)(arow);
        const fvec4 f1 = *(const fvec4*)(arow + 4);
        const fvec4 f2 = *(const fvec4*)(arow + 32);
        const fvec4 f3 = *(const fvec4*)(arow + 36);

        // A-frags via packed bf16 converts (1 inst / 2 floats)
        uvec4 ua0, ua1;
        ua0[0] = pkbf(f0[0], f0[1]);  ua0[1] = pkbf(f0[2], f0[3]);
        ua0[2] = pkbf(f1[0], f1[1]);  ua0[3] = pkbf(f1[2], f1[3]);
        ua1[0] = pkbf(f2[0], f2[1]);  ua1[1] = pkbf(f2[2], f2[3]);
        ua1[2] = pkbf(f3[0], f3[1]);  ua1[3] = pkbf(f3[2], f3[3]);
        const svec8 a0 = __builtin_bit_cast(svec8, ua0);
        const svec8 a1 = __builtin_bit_cast(svec8, ua1);

        // ---- phase 1: x = k @ Wc + qterm (qterm in acc init)
        fvec4 acc[4];
        #pragma unroll
        for (int c = 0; c < 4; ++c) {
            fvec4 a = (fvec4){qtermv[c], qtermv[c], qtermv[c], qtermv[c]};
            a = __builtin_amdgcn_mfma_f32_16x16x32_bf16(a0, wcf[c][0], a, 0, 0, 0);
            a = __builtin_amdgcn_mfma_f32_16x16x32_bf16(a1, wcf[c][1], a, 0, 0, 0);
            acc[c] = a;
        }

        // ---- dice1; h1 -> LDS in frag layout, XOR-swizzled slots
        #pragma unroll
        for (int c = 0; c < 4; ++c) {
            const int kk2 = c >> 1;
            const int qhi = (c & 1) * 2 + (m >> 3);
            #pragma unroll
            for (int reg = 0; reg < 4; ++reg) {
                const float x  = acc[c][reg];
                const float tn = (x - m1p[c]) * r1p[c];          // log2-scaled
                const float p  = __builtin_amdgcn_rcpf(1.f + exp2fast(-tn));
                const float h1 = x * fmaf(p, o1p[c], a1p[c]);
                const int l2  = (qhi << 4) | ((qd4 << 2) | reg);
                const int l2s = l2 ^ ((l2 >> 3) & 7);
                *(short*)(myh1 + (kk2 << 10) + (l2s << 4) + ((m & 7) << 1))
                    = f2bf(h1);
            }
        }
        // same-wave write->read; compiler inserts lgkmcnt, no barrier

        // ---- phase 2 (operand-swapped): h2^T = W2^T @ h1^T
        //      C[row=j=qd4*4+reg][col=seqrow=m]
        const int slot = lane ^ ((lane >> 3) & 7);
        const svec8 bb0 = *(const svec8*)(myh1 + (slot << 4));
        const svec8 bb1 = *(const svec8*)(myh1 + 1024 + (slot << 4));
        fvec4 acc2 = (fvec4){0.f, 0.f, 0.f, 0.f};
        acc2 = __builtin_amdgcn_mfma_f32_16x16x32_bf16(w2f[0], bb0, acc2, 0, 0, 0);
        acc2 = __builtin_amdgcn_mfma_f32_16x16x32_bf16(w2f[1], bb1, acc2, 0, 0, 0);

        // ---- dice2 + W3: in-lane partial over 4 j's, 2 shfl_xor over the
        //      qd4 groups -> every lane holds s for its own row rb+m
        float s = 0.f;
        #pragma unroll
        for (int reg = 0; reg < 4; ++reg) {
            const float x  = acc2[reg];
            const float tn = (x - m2p[reg]) * r2p[reg];          // log2-scaled
            const float p  = __builtin_amdgcn_rcpf(1.f + exp2fast(-tn));
            const float hd = x * fmaf(p, o2p[reg], a2p[reg]);
            s = fmaf(hd, w3p[reg], s);
        }
        s += __shfl_xor(s, 16);
        s += __shfl_xor(s, 32);
        const float w = (rb + m < nseq)
            ? __builtin_amdgcn_rcpf(1.f + exp2fast(-s * LOG2E)) : 0.f;

        // ---- phase 3: accumulate w * k-row from the registers we already
        //      hold (lane 16q+m owns row rb+m, cols q*8.. / 32+q*8..)
        #pragma unroll
        for (int jj = 0; jj < 4; ++jj) {
            oa0[jj] = fmaf(w, f0[jj], oa0[jj]);
            oa1[jj] = fmaf(w, f1[jj], oa1[jj]);
            oa2[jj] = fmaf(w, f2[jj], oa2[jj]);
            oa3[jj] = fmaf(w, f3[jj], oa3[jj]);
        }
    }

    // ---- once-per-kernel reduce over the 16 m-lanes of each q-group
    #pragma unroll
    for (int step = 1; step < 16; step <<= 1) {
        #pragma unroll
        for (int jj = 0; jj < 4; ++jj) {
            oa0[jj] += __shfl_xor(oa0[jj], step);
            oa1[jj] += __shfl_xor(oa1[jj], step);
            oa2[jj] += __shfl_xor(oa2[jj], step);
            oa3[jj] += __shfl_xor(oa3[jj], step);
        }
    }
    if (m == 0) {
        float* op = outp + wave * 64 + (qd4 << 3);
        *(fvec4*)(op)          = oa0;
        *(fvec4*)(op + 4)      = oa1;
        *(fvec4*)(op + 32)     = oa2;
        *(fvec4*)(op + 36)     = oa3;
    }
    __syncthreads();
    if (t < 64) {
        out[(size_t)b * DIM + t] = (outp[t] + outp[64 + t]) +
                                   (outp[128 + t] + outp[192 + t]);
    }
}

extern "C" void kernel_launch(void* const* d_in, const int* in_sizes, int n_in,
                              void* d_out, int out_size, void* d_ws, size_t ws_size,
                              hipStream_t stream) {
    const float* q      = (const float*)d_in[0];
    const float* key    = (const float*)d_in[1];
    const int*   seqlen = (const int*)d_in[2];
    const float* W1     = (const float*)d_in[3];
    const float* alpha1 = (const float*)d_in[4];
    const float* mean1  = (const float*)d_in[5];
    const float* var1   = (const float*)d_in[6];
    const float* W2     = (const float*)d_in[7];
    const float* alpha2 = (const float*)d_in[8];
    const float* mean2  = (const float*)d_in[9];
    const float* var2   = (const float*)d_in[10];
    const float* W3     = (const float*)d_in[11];
    float* out          = (float*)d_out;

    din_attn_kernel<<<NB, 256, 0, stream>>>(q, key, seqlen, W1,
                                            alpha1, mean1, var1,
                                            W2, alpha2, mean2, var2,
                                            W3, out);
}

// Round 7
// 180.772 us; speedup vs baseline: 1.2319x; 1.0056x over previous
//
#include <hip/hip_runtime.h>

#define NB   2048
#define SEQ  200
#define DIM  64
#define NH1  64
#define NH2  16
#define EPSF 1e-9f
#define LOG2E 1.442695040888963f

typedef float    fvec4 __attribute__((ext_vector_type(4)));
typedef short    svec8 __attribute__((ext_vector_type(8)));   // 8 bf16 = 4 VGPRs
typedef unsigned uvec4 __attribute__((ext_vector_type(4)));

// LDS layout (bytes). h1 transpose buffers alias the setup-only Wc frag
// region (fenced by the second __syncthreads).
#define WCB_OFF   0        // 8192 B : setup Wc B-frags / main-loop h1f (4 x 2KB)
#define QPART_OFF 8192     // 1024 B : qterm partials (setup) / outp (epilogue)
#define QALL_OFF  9216     // 256 B  : qterm[64]
#define SMEM_BYTES 9472

__device__ __forceinline__ short f2bf(float f) {
    unsigned u = __float_as_uint(f);
    u += 0x7fffu + ((u >> 16) & 1u);      // round-to-nearest-even
    return (short)(u >> 16);
}

// packed f32x2 -> bf16x2 (RNE), 1 instruction
__device__ __forceinline__ unsigned pkbf(float lo, float hi) {
    unsigned r;
    asm("v_cvt_pk_bf16_f32 %0, %1, %2" : "=v"(r) : "v"(lo), "v"(hi));
    return r;
}
// raw v_exp_f32: D = 2^S0
__device__ __forceinline__ float exp2fast(float x) {
    float r;
    asm("v_exp_f32 %0, %1" : "=v"(r) : "v"(x));
    return r;
}

__global__ __launch_bounds__(256, 3)
void din_attn_kernel(const float* __restrict__ q,        // [B,64]
                     const float* __restrict__ key,      // [B,200,64]
                     const int*   __restrict__ seqlen,   // [B,1]
                     const float* __restrict__ W1,       // [256,64]
                     const float* __restrict__ alpha1v,
                     const float* __restrict__ mean1v,
                     const float* __restrict__ var1v,
                     const float* __restrict__ W2,       // [64,16]
                     const float* __restrict__ alpha2v,
                     const float* __restrict__ mean2v,
                     const float* __restrict__ var2v,
                     const float* __restrict__ W3,       // [16]
                     float* __restrict__ out)            // [B,64]
{
    __shared__ __align__(16) char smem[SMEM_BYTES];
    char*  wcb   = smem + WCB_OFF;                 // setup Wc frags
    char*  h1f   = smem + WCB_OFF;                 // main-loop alias
    float* qpart = (float*)(smem + QPART_OFF);
    float* qall  = (float*)(smem + QALL_OFF);
    float* outp  = (float*)(smem + QPART_OFF);     // epilogue alias

    const int b    = blockIdx.x;
    const int t    = threadIdx.x;
    const int lane = t & 63;
    const int wave = __builtin_amdgcn_readfirstlane(t >> 6);
    const int qd4  = lane >> 4;     // quad 0..3
    const int m    = lane & 15;

    const float* qrow = q + (size_t)b * DIM;
    const float* kb   = key + (size_t)b * (SEQ * DIM);
    int nseq = seqlen[b];
    nseq = nseq < SEQ ? nseq : SEQ;

    // ---- first k-tile loads issued BEFORE setup: their ~600-900 cy latency
    //      hides under the W1 loads + both barriers.  Clamped row -> always
    //      safe to load, garbage rows get weight 0 later.
    int rm0 = wave * 16 + m;
    rm0 = rm0 < SEQ ? rm0 : SEQ - 1;
    const float* arow0 = kb + rm0 * DIM + (qd4 << 3);
    fvec4 f0 = *(const fvec4*)(arow0);
    fvec4 f1 = *(const fvec4*)(arow0 + 4);
    fvec4 f2 = *(const fvec4*)(arow0 + 32);
    fvec4 f3 = *(const fvec4*)(arow0 + 36);

    // ---- setup 1: Wc = (W1b - W1c) + q[d]*W1d written as bf16 in frag
    //      layout; qterm partials.  Element (d,h) -> frag=(h>>4)*2+(d>>5),
    //      slot=((d>>3)&3)*16+(h&15), byte j=(d&7)*2.
    {
        const int h  = lane;
        const int c  = h >> 4;
        const int mm = h & 15;
        float qt = 0.f;
        #pragma unroll
        for (int i = 0; i < 16; ++i) {
            const int d = wave * 16 + i;
            const float qdv  = qrow[d];
            const float w1a  = W1[(d)       * NH1 + h];
            const float w1b  = W1[(64 + d)  * NH1 + h];
            const float w1c  = W1[(128 + d) * NH1 + h];
            const float w1dd = W1[(192 + d) * NH1 + h];
            const float wc   = (w1b - w1c) + qdv * w1dd;
            qt = fmaf(qdv, w1a + w1c, qt);
            const int frag = (c << 1) | (d >> 5);
            const int ln   = (((d >> 3) & 3) << 4) | mm;
            *(short*)(wcb + (frag << 10) + (ln << 4) + ((d & 7) << 1)) = f2bf(wc);
        }
        qpart[wave * 64 + h] = qt;
    }
    __syncthreads();

    // ---- setup 2: qterm reduce; frags to registers; params
    if (t < 64)
        qall[t] = (qpart[t] + qpart[64 + t]) + (qpart[128 + t] + qpart[192 + t]);

    svec8 wcf[4][2];   // Wc B-frags (phase-1 B operand)
    #pragma unroll
    for (int c = 0; c < 4; ++c)
        #pragma unroll
        for (int kk = 0; kk < 2; ++kk)
            wcf[c][kk] = *(const svec8*)(wcb + (((c << 1) | kk) << 10) + (lane << 4));

    // W2 frags, consumed as the *A* operand of the transposed phase-2:
    // A[row=j=m][k=h=kk*32+qd4*8+jj] = W2[h][j].
    svec8 w2f[2];
    #pragma unroll
    for (int kk = 0; kk < 2; ++kk) {
        svec8 f;
        #pragma unroll
        for (int j = 0; j < 8; ++j) {
            const int h = kk * 32 + qd4 * 8 + j;
            f[j] = f2bf(W2[h * NH2 + m]);
        }
        w2f[kk] = f;
    }

    // dice1 params for h = c*16 + m; r1p pre-scaled by log2(e) (raw v_exp)
    float a1p[4], o1p[4], m1p[4], r1p[4];
    #pragma unroll
    for (int c = 0; c < 4; ++c) {
        a1p[c] = alpha1v[c * 16 + m];
        o1p[c] = 1.f - a1p[c];
        m1p[c] = mean1v[c * 16 + m];
        r1p[c] = rsqrtf(var1v[c * 16 + m] + EPSF) * LOG2E;
    }
    // dice2 params for j = qd4*4 + reg (transposed phase-2 output rows)
    float a2p[4], o2p[4], m2p[4], r2p[4], w3p[4];
    #pragma unroll
    for (int reg = 0; reg < 4; ++reg) {
        const int j = qd4 * 4 + reg;
        a2p[reg] = alpha2v[j];
        o2p[reg] = 1.f - a2p[reg];
        m2p[reg] = mean2v[j];
        r2p[reg] = rsqrtf(var2v[j] + EPSF) * LOG2E;
        w3p[reg] = W3[j];
    }

    __syncthreads();   // wcb reads done -> h1f alias safe; qall ready

    float qtermv[4];
    #pragma unroll
    for (int c = 0; c < 4; ++c) qtermv[c] = qall[c * 16 + m];

    char* myh1 = h1f + (wave << 11);   // 2 KB private transpose buffer

    fvec4 oa0 = (fvec4){0.f,0.f,0.f,0.f};   // out cols qd4*8+0..3
    fvec4 oa1 = (fvec4){0.f,0.f,0.f,0.f};   // out cols qd4*8+4..7
    fvec4 oa2 = (fvec4){0.f,0.f,0.f,0.f};   // out cols 32+qd4*8+0..3
    fvec4 oa3 = (fvec4){0.f,0.f,0.f,0.f};   // out cols 32+qd4*8+4..7

    // ---- barrier-free rotated main loop: wave owns rows [rb, rb+16),
    //      rb += 64.  Next tile prefetched UNCONDITIONALLY (clamped row) so
    //      there are no conditionally-defined registers (round-3 spill trap).
    int rb = wave * 16;
    if (rb < nseq) {
        for (;;) {
            const int rbn = rb + 64;
            int rn = rbn + m;
            rn = rn < SEQ ? rn : SEQ - 1;
            const float* brow = kb + rn * DIM + (qd4 << 3);
            const fvec4 g0 = *(const fvec4*)(brow);
            const fvec4 g1 = *(const fvec4*)(brow + 4);
            const fvec4 g2 = *(const fvec4*)(brow + 32);
            const fvec4 g3 = *(const fvec4*)(brow + 36);

            // A-frags via packed bf16 converts (1 inst / 2 floats)
            uvec4 ua0, ua1;
            ua0[0] = pkbf(f0[0], f0[1]);  ua0[1] = pkbf(f0[2], f0[3]);
            ua0[2] = pkbf(f1[0], f1[1]);  ua0[3] = pkbf(f1[2], f1[3]);
            ua1[0] = pkbf(f2[0], f2[1]);  ua1[1] = pkbf(f2[2], f2[3]);
            ua1[2] = pkbf(f3[0], f3[1]);  ua1[3] = pkbf(f3[2], f3[3]);
            const svec8 a0 = __builtin_bit_cast(svec8, ua0);
            const svec8 a1 = __builtin_bit_cast(svec8, ua1);

            // ---- phase 1: x = k @ Wc + qterm (qterm in acc init)
            fvec4 acc[4];
            #pragma unroll
            for (int c = 0; c < 4; ++c) {
                fvec4 a = (fvec4){qtermv[c], qtermv[c], qtermv[c], qtermv[c]};
                a = __builtin_amdgcn_mfma_f32_16x16x32_bf16(a0, wcf[c][0], a, 0, 0, 0);
                a = __builtin_amdgcn_mfma_f32_16x16x32_bf16(a1, wcf[c][1], a, 0, 0, 0);
                acc[c] = a;
            }

            // ---- dice1; h1 -> LDS in frag layout, XOR-swizzled slots
            #pragma unroll
            for (int c = 0; c < 4; ++c) {
                const int kk2 = c >> 1;
                const int qhi = (c & 1) * 2 + (m >> 3);
                #pragma unroll
                for (int reg = 0; reg < 4; ++reg) {
                    const float x  = acc[c][reg];
                    const float tn = (x - m1p[c]) * r1p[c];      // log2-scaled
                    const float p  = __builtin_amdgcn_rcpf(1.f + exp2fast(-tn));
                    const float h1 = x * fmaf(p, o1p[c], a1p[c]);
                    const int l2  = (qhi << 4) | ((qd4 << 2) | reg);
                    const int l2s = l2 ^ ((l2 >> 3) & 7);
                    *(short*)(myh1 + (kk2 << 10) + (l2s << 4) + ((m & 7) << 1))
                        = f2bf(h1);
                }
            }
            // same-wave write->read; compiler inserts lgkmcnt, no barrier

            // ---- phase 2 (operand-swapped): h2^T = W2^T @ h1^T
            //      C[row=j=qd4*4+reg][col=seqrow=m]
            const int slot = lane ^ ((lane >> 3) & 7);
            const svec8 bb0 = *(const svec8*)(myh1 + (slot << 4));
            const svec8 bb1 = *(const svec8*)(myh1 + 1024 + (slot << 4));
            fvec4 acc2 = (fvec4){0.f, 0.f, 0.f, 0.f};
            acc2 = __builtin_amdgcn_mfma_f32_16x16x32_bf16(w2f[0], bb0, acc2, 0, 0, 0);
            acc2 = __builtin_amdgcn_mfma_f32_16x16x32_bf16(w2f[1], bb1, acc2, 0, 0, 0);

            // ---- dice2 + W3: in-lane partial over 4 j's, 2 shfl_xor over
            //      the qd4 groups -> every lane holds s for its own row rb+m
            float s = 0.f;
            #pragma unroll
            for (int reg = 0; reg < 4; ++reg) {
                const float x  = acc2[reg];
                const float tn = (x - m2p[reg]) * r2p[reg];      // log2-scaled
                const float p  = __builtin_amdgcn_rcpf(1.f + exp2fast(-tn));
                const float hd = x * fmaf(p, o2p[reg], a2p[reg]);
                s = fmaf(hd, w3p[reg], s);
            }
            s += __shfl_xor(s, 16);
            s += __shfl_xor(s, 32);
            const float w = (rb + m < nseq)
                ? __builtin_amdgcn_rcpf(1.f + exp2fast(-s * LOG2E)) : 0.f;

            // ---- phase 3: accumulate w * k-row from registers we hold
            #pragma unroll
            for (int jj = 0; jj < 4; ++jj) {
                oa0[jj] = fmaf(w, f0[jj], oa0[jj]);
                oa1[jj] = fmaf(w, f1[jj], oa1[jj]);
                oa2[jj] = fmaf(w, f2[jj], oa2[jj]);
                oa3[jj] = fmaf(w, f3[jj], oa3[jj]);
            }

            if (rbn >= nseq) break;                    // wave-uniform
            rb = rbn;
            f0 = g0; f1 = g1; f2 = g2; f3 = g3;
        }
    }

    // ---- once-per-kernel reduce over the 16 m-lanes of each q-group
    #pragma unroll
    for (int step = 1; step < 16; step <<= 1) {
        #pragma unroll
        for (int jj = 0; jj < 4; ++jj) {
            oa0[jj] += __shfl_xor(oa0[jj], step);
            oa1[jj] += __shfl_xor(oa1[jj], step);
            oa2[jj] += __shfl_xor(oa2[jj], step);
            oa3[jj] += __shfl_xor(oa3[jj], step);
        }
    }
    if (m == 0) {
        float* op = outp + wave * 64 + (qd4 << 3);
        *(fvec4*)(op)          = oa0;
        *(fvec4*)(op + 4)      = oa1;
        *(fvec4*)(op + 32)     = oa2;
        *(fvec4*)(op + 36)     = oa3;
    }
    __syncthreads();
    if (t < 64) {
        out[(size_t)b * DIM + t] = (outp[t] + outp[64 + t]) +
                                   (outp[128 + t] + outp[192 + t]);
    }
}

extern "C" void kernel_launch(void* const* d_in, const int* in_sizes, int n_in,
                              void* d_out, int out_size, void* d_ws, size_t ws_size,
                              hipStream_t stream) {
    const float* q      = (const float*)d_in[0];
    const float* key    = (const float*)d_in[1];
    const int*   seqlen = (const int*)d_in[2];
    const float* W1     = (const float*)d_in[3];
    const float* alpha1 = (const float*)d_in[4];
    const float* mean1  = (const float*)d_in[5];
    const float* var1   = (const float*)d_in[6];
    const float* W2     = (const float*)d_in[7];
    const float* alpha2 = (const float*)d_in[8];
    const float* mean2  = (const float*)d_in[9];
    const float* var2   = (const float*)d_in[10];
    const float* W3     = (const float*)d_in[11];
    float* out          = (float*)d_out;

    din_attn_kernel<<<NB, 256, 0, stream>>>(q, key, seqlen, W1,
                                            alpha1, mean1, var1,
                                            W2, alpha2, mean2, var2,
                                            W3, out);
}